// Round 4
// baseline (704.353 us; speedup 1.0000x reference)
//
#include <hip/hip_runtime.h>
#include <hip/hip_bf16.h>

// MolGAN discriminator: 3x RGCN(+BN over atom axis+LeakyReLU) + masked-sum readout.
// R4: k_mfma rewrite. buildY vectorized: adj rows in registers (loaded once), h read as
// b128 and converted once per k-chunk (reused across all 4 relations), v_pk_fma_f32 via
// f32x2, leaky = fmax(v, 0.2v). K-loop: per 32-col chunk {build 4 relations -> barrier ->
// 16*NT MFMA burst -> barrier}; yS row stride 56 elems (conflict-free b128, 16B aligned).
// Path A (ws >= 227 MB): store h2 + readout pass. Path B: layer-2 twice (stats, readout).

#define NB 32768
#define NA 9
#define NR 4
#define D0 5
#define D1 64
#define D2 128
#define D3 256
#define EPS 1e-5f
#define SLOPE 0.2f
#define NSLOT 64
#define YST 56   // yS row stride (elems): 112B -> bank period 8 rows, b128-aligned

typedef __hip_bfloat16 bf16;
typedef short bf16x8 __attribute__((ext_vector_type(8)));
typedef float f32x4 __attribute__((ext_vector_type(4)));
typedef float f32x2 __attribute__((ext_vector_type(2)));

__device__ __forceinline__ float bf2f(bf16 v) { return __bfloat162float(v); }
__device__ __forceinline__ bf16  f2bf(float v) { return __float2bfloat16(v); }

// bf16x8 -> 4x f32x2 (pairs preserve element order)
__device__ __forceinline__ void cvt8(bf16x8 v, f32x2 out[4]) {
    union { bf16x8 h; unsigned u[4]; } cv; cv.h = v;
    #pragma unroll
    for (int j = 0; j < 4; j++) {
        out[j].x = __uint_as_float(cv.u[j] << 16);
        out[j].y = __uint_as_float(cv.u[j] & 0xffff0000u);
    }
}

__device__ __forceinline__ bf16x8 pack8(const f32x2 y[4]) {
    union { bf16x8 h; unsigned short s[8]; } cv;
    #pragma unroll
    for (int j = 0; j < 4; j++) {
        union { bf16 b; unsigned short s; } t0, t1;
        t0.b = f2bf(y[j].x); t1.b = f2bf(y[j].y);
        cv.s[2*j] = t0.s; cv.s[2*j+1] = t1.s;
    }
    return cv.h;
}

// ---------------- zero init ----------------
__global__ __launch_bounds__(256) void k_zero(float* __restrict__ hdr, float* __restrict__ out)
{
    int idx = blockIdx.x * 256 + threadIdx.x;
    if (idx < NB) out[idx] = 0.f;
    if (idx < 6240) hdr[idx] = 0.f;
}

// ---------------- weight prep: Wcat^T [DOUT][5*DIN] bf16 ----------------
template<int DIN, int DOUT>
__global__ __launch_bounds__(256) void k_prep(const float* __restrict__ ws,
                                              const float* __restrict__ wr,
                                              bf16* __restrict__ wt)
{
    constexpr int K5 = 5*DIN;
    int idx = blockIdx.x*256 + threadIdx.x;
    if (idx >= DOUT*K5) return;
    int n = idx / K5, k = idx % K5;
    int s = k / DIN, kk = k % DIN;
    float v = (s == 0) ? ws[(size_t)kk*DOUT + n]
                       : wr[((size_t)(s-1)*DIN + kk)*DOUT + n];
    wt[idx] = f2bf(v);
}

// ---------------- layer 0 (din=5) ----------------
__global__ __launch_bounds__(256) void k_layer0(
    const float* __restrict__ feats, const float* __restrict__ adj,
    const float* __restrict__ ws, const float* __restrict__ wr,
    const float* __restrict__ bias, bf16* __restrict__ hpre, float* __restrict__ slots)
{
    __shared__ float Wsh[5][5][64];
    __shared__ float Bsh[64];
    __shared__ float Adj[4][4][9][9];
    __shared__ float Hsh[4][9][5];
    __shared__ float bstat[18];

    int tid = threadIdx.x;
    int bl  = tid >> 6;
    int e   = tid & 63;
    int b0  = blockIdx.x * 4;

    for (int i = tid; i < 5*64; i += 256) Wsh[0][i/64][i%64] = ws[i];
    for (int i = tid; i < 4*5*64; i += 256) {
        int s = i / 320, rem = i % 320;
        Wsh[1+s][rem/64][rem%64] = wr[i];
    }
    if (tid < 64) Bsh[tid] = bias[tid];
    if (tid < 18) bstat[tid] = 0.f;
    {
        const float* ap = adj + (size_t)(b0 + bl) * (NR*NA*NA);
        float* dst = &Adj[bl][0][0][0];
        for (int i = e; i < NR*NA*NA; i += 64) dst[i] = ap[i];
    }
    {
        const float* fp = feats + (size_t)(b0 + bl) * (NA*D0);
        float* dst = &Hsh[bl][0][0];
        for (int i = e; i < NA*D0; i += 64) dst[i] = fp[i];
    }
    __syncthreads();

    float X[5][9];
    #pragma unroll
    for (int s = 0; s < 5; s++)
        #pragma unroll
        for (int n = 0; n < 9; n++) {
            float a = 0.f;
            #pragma unroll
            for (int k = 0; k < 5; k++) a += Hsh[bl][n][k] * Wsh[s][k][e];
            X[s][n] = a;
        }
    float bv = Bsh[e];
    float out[9];
    #pragma unroll
    for (int m = 0; m < 9; m++) {
        float a = X[0][m] + bv;
        #pragma unroll
        for (int r = 0; r < 4; r++)
            #pragma unroll
            for (int n = 0; n < 9; n++)
                a += Adj[bl][r][m][n] * X[1+r][n];
        out[m] = a;
    }
    bf16* hp = hpre + (size_t)(b0 + bl) * (NA*D1) + e;
    #pragma unroll
    for (int m = 0; m < 9; m++) hp[m*D1] = f2bf(out[m]);

    #pragma unroll
    for (int m = 0; m < 9; m++) {
        float s = out[m], q = out[m]*out[m];
        #pragma unroll
        for (int off = 32; off > 0; off >>= 1) {
            s += __shfl_xor(s, off, 64);
            q += __shfl_xor(q, off, 64);
        }
        if (e == 0) { atomicAdd(&bstat[m], s); atomicAdd(&bstat[9+m], q); }
    }
    __syncthreads();
    if (tid < 9) {
        float* sl = slots + (size_t)(blockIdx.x & (NSLOT-1)) * 32;
        atomicAdd(&sl[tid],      bstat[tid]);
        atomicAdd(&sl[16+tid],   bstat[9+tid]);
    }
}

// ---------------- BN finalize ----------------
template<int DOUT>
__global__ void k_finalize(const float* __restrict__ slots,
                           const float* __restrict__ g, const float* __restrict__ be,
                           float* __restrict__ fin)
{
    int n = threadIdx.x;
    if (n < 9) {
        float s = 0.f, q = 0.f;
        for (int i = 0; i < NSLOT; i++) { s += slots[i*32+n]; q += slots[i*32+16+n]; }
        float cnt = (float)NB * (float)DOUT;
        float mean = s / cnt;
        float var  = q / cnt - mean*mean;
        float sc   = g[n] * rsqrtf(var + EPS);
        fin[n]    = sc;
        fin[16+n] = be[n] - mean * sc;
    }
}

// ---------------- fused RGCN layer (MFMA) ----------------
// MODE 0: store hout + stats.  MODE 1: stats only.  MODE 2: fused readout epilogue.
template<int DIN, int DOUT, int MODE>
__global__ __launch_bounds__(256, 3) void k_mfma(
    const bf16*  __restrict__ hprev,   // [B,9,DIN]
    const float* __restrict__ finPrev, // prev-layer BN affine [32]
    const float* __restrict__ adjg,    // [B,4,9,9]
    const bf16*  __restrict__ wt,      // [DOUT][5*DIN] bf16 (Wcat^T)
    const float* __restrict__ bias,    // [DOUT]
    bf16*  __restrict__ hout,          // (MODE 0)
    float* __restrict__ slots,         // (MODE 0/1)
    const float* __restrict__ finC,    // (MODE 2)
    const float* __restrict__ maskg,   // (MODE 2)
    const float* __restrict__ fcw,     // (MODE 2)
    float* __restrict__ outp)          // (MODE 2)
{
    constexpr int K5 = 5*DIN;
    constexpr int HS = DIN + 8;        // 16B-aligned row stride
    constexpr int NT = DOUT/64;
    constexpr int KS = DIN/32;         // k-chunks (32 cols each)
    constexpr int HW8 = DIN/8;

    __shared__ __align__(16) bf16 hS[81*HS];
    __shared__ __align__(16) bf16 yS[4*64*YST];
    __shared__ float rstat[128];
    __shared__ float sfinP[32];
    __shared__ float sfinC[32];

    int tid = threadIdx.x;
    int row0 = blockIdx.x * 64;
    int mol_lo = row0 / 9;
    int mol_hi = (row0 + 63) / 9;
    int nmol = mol_hi - mol_lo + 1;
    int off = row0 - mol_lo*9;

    if (tid < 32) sfinP[tid] = finPrev[tid];
    if constexpr (MODE == 2) { if (tid >= 32 && tid < 64) sfinC[tid-32] = finC[tid-32]; }
    if (tid >= 64 && tid < 192) rstat[tid-64] = 0.f;

    // buildY work assignment: thread -> (row_l, 8-col group); adj rows -> registers
    int brow = tid >> 2;
    int bc8  = (tid & 3) * 8;
    int bloc = off + brow;
    int bml  = bloc / 9;
    int ba   = bloc - bml*9;
    float adjR[4][9];
    {
        const float* ap = adjg + (size_t)(mol_lo + bml)*324 + ba*9;
        #pragma unroll
        for (int r = 0; r < 4; r++)
            #pragma unroll
            for (int n = 0; n < 9; n++) adjR[r][n] = ap[r*81 + n];
    }
    __syncthreads();

    // stage act(h_prev) -> hS (bf16, padded rows): affine(prev BN) + leaky via fmax
    for (int i = tid; i < nmol*9*HW8; i += 256) {
        int rl = i / HW8;
        int a  = rl % 9;
        int c8 = (i % HW8)*8;
        bf16x8 hv = *(const bf16x8*)(hprev + (size_t)(mol_lo*9 + rl)*DIN + c8);
        f32x2 hf[4]; cvt8(hv, hf);
        float sc = sfinP[a], sh = sfinP[16+a];
        f32x2 o[4];
        #pragma unroll
        for (int j = 0; j < 4; j++) {
            float v0 = sc*hf[j].x + sh; v0 = fmaxf(v0, SLOPE*v0);
            float v1 = sc*hf[j].y + sh; v1 = fmaxf(v1, SLOPE*v1);
            o[j] = (f32x2){v0, v1};
        }
        *(bf16x8*)(&hS[rl*HS + c8]) = pack8(o);
    }
    __syncthreads();

    int wv = tid >> 6, lane = tid & 63;
    int q = lane >> 4, l15 = lane & 15;

    f32x4 acc[4][NT];
    #pragma unroll
    for (int mt = 0; mt < 4; mt++)
        #pragma unroll
        for (int t = 0; t < NT; t++) acc[mt][t] = (f32x4){0.f, 0.f, 0.f, 0.f};

    const bf16* wp[NT];
    #pragma unroll
    for (int t = 0; t < NT; t++)
        wp[t] = wt + (size_t)((wv*NT + t)*16 + l15)*K5 + q*8;

    // --- self section: A-frags from hS ---
    #pragma unroll
    for (int ks = 0; ks < KS; ks++) {
        bf16x8 Af[4], Bf[NT];
        #pragma unroll
        for (int mt = 0; mt < 4; mt++)
            Af[mt] = *(const bf16x8*)(hS + (size_t)(off + mt*16 + l15)*HS + ks*32 + q*8);
        #pragma unroll
        for (int t = 0; t < NT; t++)
            Bf[t] = *(const bf16x8*)(wp[t] + ks*32);
        #pragma unroll
        for (int mt = 0; mt < 4; mt++)
            #pragma unroll
            for (int t = 0; t < NT; t++)
                acc[mt][t] = __builtin_amdgcn_mfma_f32_16x16x32_bf16(Af[mt], Bf[t], acc[mt][t], 0, 0, 0);
    }

    // --- relation sections: per k-chunk, build 4 relations then MFMA burst ---
    for (int kc = 0; kc < KS; kc++) {
        {   // build Y[r][64][32-cols] for this chunk; h cvt shared across relations
            const bf16* hb = hS + (size_t)(bml*9)*HS + kc*32 + bc8;
            f32x2 y[4][4];
            #pragma unroll
            for (int r = 0; r < 4; r++)
                #pragma unroll
                for (int j = 0; j < 4; j++) y[r][j] = (f32x2){0.f, 0.f};
            #pragma unroll
            for (int n = 0; n < 9; n++) {
                bf16x8 hv = *(const bf16x8*)(hb + n*HS);
                f32x2 hf[4]; cvt8(hv, hf);
                #pragma unroll
                for (int r = 0; r < 4; r++) {
                    f32x2 av = (f32x2){adjR[r][n], adjR[r][n]};
                    #pragma unroll
                    for (int j = 0; j < 4; j++)
                        y[r][j] = __builtin_elementwise_fma(av, hf[j], y[r][j]);
                }
            }
            #pragma unroll
            for (int r = 0; r < 4; r++)
                *(bf16x8*)(&yS[(r*64 + brow)*YST + bc8]) = pack8(y[r]);
        }
        __syncthreads();
        #pragma unroll
        for (int r = 0; r < 4; r++) {
            int kcol = DIN + (r*KS + kc)*32;
            bf16x8 Af[4], Bf[NT];
            #pragma unroll
            for (int mt = 0; mt < 4; mt++)
                Af[mt] = *(const bf16x8*)(&yS[(r*64 + mt*16 + l15)*YST + q*8]);
            #pragma unroll
            for (int t = 0; t < NT; t++)
                Bf[t] = *(const bf16x8*)(wp[t] + kcol);
            #pragma unroll
            for (int mt = 0; mt < 4; mt++)
                #pragma unroll
                for (int t = 0; t < NT; t++)
                    acc[mt][t] = __builtin_amdgcn_mfma_f32_16x16x32_bf16(Af[mt], Bf[t], acc[mt][t], 0, 0, 0);
        }
        __syncthreads();
    }

    // --- epilogue ---
    float bcol[NT];
    #pragma unroll
    for (int t = 0; t < NT; t++) bcol[t] = bias[(wv*NT + t)*16 + l15];

    if constexpr (MODE == 2) {
        float fwv[NT];
        #pragma unroll
        for (int t = 0; t < NT; t++) fwv[t] = fcw[(wv*NT + t)*16 + l15];
        #pragma unroll
        for (int mt = 0; mt < 4; mt++) {
            #pragma unroll
            for (int reg = 0; reg < 4; reg++) {
                int rloc = mt*16 + q*4 + reg;
                int atom = (row0 + rloc) % 9;
                float sc = sfinC[atom], sh = sfinC[16+atom];
                float part = 0.f;
                #pragma unroll
                for (int t = 0; t < NT; t++) {
                    float v = acc[mt][t][reg] + bcol[t];
                    float y = sc*v + sh;
                    y = fmaxf(y, SLOPE*y);
                    part += y * fwv[t];
                }
                part += __shfl_xor(part, 1); part += __shfl_xor(part, 2);
                part += __shfl_xor(part, 4); part += __shfl_xor(part, 8);
                if (l15 == 0) atomicAdd(&rstat[rloc], part);
            }
        }
        __syncthreads();
        if (tid < 64) {
            int rg = row0 + tid;
            int b = rg / 9;
            atomicAdd(&outp[b], rstat[tid] * maskg[rg]);
        }
        return;
    }

    #pragma unroll
    for (int mt = 0; mt < 4; mt++) {
        #pragma unroll
        for (int reg = 0; reg < 4; reg++) {
            int rloc = mt*16 + q*4 + reg;
            float s = 0.f, qq = 0.f;
            #pragma unroll
            for (int t = 0; t < NT; t++) {
                float v = acc[mt][t][reg] + bcol[t];
                if constexpr (MODE == 0) {
                    size_t o = (size_t)(row0 + rloc)*DOUT + (wv*NT + t)*16 + l15;
                    hout[o] = f2bf(v);
                }
                s += v; qq += v*v;
            }
            s += __shfl_xor(s, 1); s += __shfl_xor(s, 2);
            s += __shfl_xor(s, 4); s += __shfl_xor(s, 8);
            qq += __shfl_xor(qq, 1); qq += __shfl_xor(qq, 2);
            qq += __shfl_xor(qq, 4); qq += __shfl_xor(qq, 8);
            if (l15 == 0) { atomicAdd(&rstat[rloc*2], s); atomicAdd(&rstat[rloc*2+1], qq); }
        }
    }
    __syncthreads();
    if (tid < 64) {
        int rg = row0 + tid;
        int atom = rg % 9;
        float* sl = slots + (size_t)(blockIdx.x & (NSLOT-1))*32;
        atomicAdd(&sl[atom],    rstat[tid*2]);
        atomicAdd(&sl[16+atom], rstat[tid*2+1]);
    }
}

// ---------------- Path-A readout ----------------
__global__ __launch_bounds__(256) void k_readout(
    const bf16* __restrict__ h2, const float* __restrict__ fin,
    const float* __restrict__ mask, const float* __restrict__ fcw,
    const float* __restrict__ fcb, float* __restrict__ out)
{
    int tid = threadIdx.x;
    int w = tid >> 6, lane = tid & 63;
    int b = blockIdx.x * 4 + w;
    float sc[9], sh[9];
    #pragma unroll
    for (int n = 0; n < 9; n++) { sc[n] = fin[n]; sh[n] = fin[16+n]; }
    const bf16* hp = h2 + (size_t)b * (NA*D3) + lane*4;
    float acc0 = 0.f, acc1 = 0.f, acc2 = 0.f, acc3 = 0.f;
    #pragma unroll
    for (int n = 0; n < 9; n++) {
        bf16 v4[4] __attribute__((aligned(8)));
        *(uint2*)v4 = *(const uint2*)(hp + n*D3);
        float mk = mask[(size_t)b*NA + n];
        float v;
        v = sc[n]*bf2f(v4[0]) + sh[n]; v = fmaxf(v, SLOPE*v); acc0 += v*mk;
        v = sc[n]*bf2f(v4[1]) + sh[n]; v = fmaxf(v, SLOPE*v); acc1 += v*mk;
        v = sc[n]*bf2f(v4[2]) + sh[n]; v = fmaxf(v, SLOPE*v); acc2 += v*mk;
        v = sc[n]*bf2f(v4[3]) + sh[n]; v = fmaxf(v, SLOPE*v); acc3 += v*mk;
    }
    float4 wv = *(const float4*)(fcw + lane*4);
    float s = acc0*wv.x + acc1*wv.y + acc2*wv.z + acc3*wv.w;
    #pragma unroll
    for (int off = 1; off < 64; off <<= 1) s += __shfl_xor(s, off, 64);
    if (lane == 0) out[b] = s + fcb[0];
}

__global__ __launch_bounds__(256) void k_addfcb(float* __restrict__ out, const float* __restrict__ fcb)
{
    int idx = blockIdx.x * 256 + threadIdx.x;
    if (idx < NB) out[idx] += fcb[0];
}

// ---------------- workspace layout (see R3 comment; unchanged) ----------------

extern "C" void kernel_launch(void* const* d_in, const int* in_sizes, int n_in,
                              void* d_out, int out_size, void* d_ws, size_t ws_size,
                              hipStream_t stream)
{
    const float* feats = (const float*)d_in[0];
    const float* adj   = (const float*)d_in[1];
    const float* mask  = (const float*)d_in[2];
    const float* ws0 = (const float*)d_in[3];
    const float* wr0 = (const float*)d_in[4];
    const float* b0  = (const float*)d_in[5];
    const float* g0  = (const float*)d_in[6];
    const float* be0 = (const float*)d_in[7];
    const float* ws1 = (const float*)d_in[8];
    const float* wr1 = (const float*)d_in[9];
    const float* b1  = (const float*)d_in[10];
    const float* g1  = (const float*)d_in[11];
    const float* be1 = (const float*)d_in[12];
    const float* ws2 = (const float*)d_in[13];
    const float* wr2 = (const float*)d_in[14];
    const float* b2  = (const float*)d_in[15];
    const float* g2  = (const float*)d_in[16];
    const float* be2 = (const float*)d_in[17];
    const float* fcw = (const float*)d_in[18];
    const float* fcb = (const float*)d_in[19];
    float* outp = (float*)d_out;

    char* wsb = (char*)d_ws;
    float* slots0 = (float*)(wsb + 0);
    float* slots1 = slots0 + NSLOT*32;
    float* slots2 = slots1 + NSLOT*32;
    float* fin0 = (float*)(wsb + 24576);
    float* fin1 = fin0 + 32;
    float* fin2 = fin1 + 32;
    bf16* wt1 = (bf16*)(wsb + 32768);
    bf16* wt2 = (bf16*)(wsb + 114688);

    k_zero<<<(NB+255)/256, 256, 0, stream>>>((float*)wsb, outp);
    k_prep<D1, D2><<<(D2*5*D1 + 255)/256, 256, 0, stream>>>(ws1, wr1, wt1);
    k_prep<D2, D3><<<(D3*5*D2 + 255)/256, 256, 0, stream>>>(ws2, wr2, wt2);

    bool bigws = (ws_size >= 227016704ULL);
    const int GRID = (NB*NA)/64;   // 4608

    if (bigws) {
        bf16* h1 = (bf16*)(wsb + 524288ULL);
        bf16* h2 = (bf16*)(wsb + 76021760ULL);
        bf16* h0 = h2;   // alias: h0 fully consumed before first h2 write

        k_layer0<<<NB/4, 256, 0, stream>>>(feats, adj, ws0, wr0, b0, h0, slots0);
        k_finalize<D1><<<1, 64, 0, stream>>>(slots0, g0, be0, fin0);

        k_mfma<D1, D2, 0><<<GRID, 256, 0, stream>>>(
            h0, fin0, adj, wt1, b1, h1, slots1, nullptr, nullptr, nullptr, nullptr);
        k_finalize<D2><<<1, 64, 0, stream>>>(slots1, g1, be1, fin1);

        k_mfma<D2, D3, 0><<<GRID, 256, 0, stream>>>(
            h1, fin1, adj, wt2, b2, h2, slots2, nullptr, nullptr, nullptr, nullptr);
        k_finalize<D3><<<1, 64, 0, stream>>>(slots2, g2, be2, fin2);

        k_readout<<<NB/4, 256, 0, stream>>>(h2, fin2, mask, fcw, fcb, outp);
    } else {
        bf16* h0 = (bf16*)(wsb + 524288ULL);
        bf16* h1 = (bf16*)(wsb + 38273024ULL);

        k_layer0<<<NB/4, 256, 0, stream>>>(feats, adj, ws0, wr0, b0, h0, slots0);
        k_finalize<D1><<<1, 64, 0, stream>>>(slots0, g0, be0, fin0);

        k_mfma<D1, D2, 0><<<GRID, 256, 0, stream>>>(
            h0, fin0, adj, wt1, b1, h1, slots1, nullptr, nullptr, nullptr, nullptr);
        k_finalize<D2><<<1, 64, 0, stream>>>(slots1, g1, be1, fin1);

        k_mfma<D2, D3, 1><<<GRID, 256, 0, stream>>>(
            h1, fin1, adj, wt2, b2, nullptr, slots2, nullptr, nullptr, nullptr, nullptr);
        k_finalize<D3><<<1, 64, 0, stream>>>(slots2, g2, be2, fin2);

        k_mfma<D2, D3, 2><<<GRID, 256, 0, stream>>>(
            h1, fin1, adj, wt2, b2, nullptr, nullptr, fin2, mask, fcw, outp);
        k_addfcb<<<(NB+255)/256, 256, 0, stream>>>(outp, fcb);
    }
}

// Round 5
// 612.543 us; speedup vs baseline: 1.1499x; 1.1499x over previous
//
#include <hip/hip_runtime.h>
#include <hip/hip_bf16.h>

// MolGAN discriminator: 3x RGCN(+BN over atom axis+LeakyReLU) + masked-sum readout.
// R5: fix R4's VGPR spill (launch_bounds(256,2) -> 256-reg budget; R4's (256,3) capped
// at ~170 and spilled 400+MB/dispatch to scratch). buildY kept vectorized: adj rows in
// registers, h cvt shared across 4 relations, pk_fma. yS double-buffered -> ONE barrier
// per k-chunk (build kc+1 overlaps MFMA on kc). Path A (ws>=250MB, confirmed live):
// h2 stored, layer-2 GEMM runs once.

#define NB 32768
#define NA 9
#define NR 4
#define D0 5
#define D1 64
#define D2 128
#define D3 256
#define EPS 1e-5f
#define SLOPE 0.2f
#define NSLOT 64
#define YST 56   // yS row stride (elems): 112B -> 2-way b128 bank aliasing (free)

typedef __hip_bfloat16 bf16;
typedef short bf16x8 __attribute__((ext_vector_type(8)));
typedef float f32x4 __attribute__((ext_vector_type(4)));
typedef float f32x2 __attribute__((ext_vector_type(2)));

__device__ __forceinline__ float bf2f(bf16 v) { return __bfloat162float(v); }
__device__ __forceinline__ bf16  f2bf(float v) { return __float2bfloat16(v); }

__device__ __forceinline__ void cvt8(bf16x8 v, f32x2 out[4]) {
    union { bf16x8 h; unsigned u[4]; } cv; cv.h = v;
    #pragma unroll
    for (int j = 0; j < 4; j++) {
        out[j].x = __uint_as_float(cv.u[j] << 16);
        out[j].y = __uint_as_float(cv.u[j] & 0xffff0000u);
    }
}

__device__ __forceinline__ bf16x8 pack8(const f32x2 y[4]) {
    union { bf16x8 h; unsigned short s[8]; } cv;
    #pragma unroll
    for (int j = 0; j < 4; j++) {
        union { bf16 b; unsigned short s; } t0, t1;
        t0.b = f2bf(y[j].x); t1.b = f2bf(y[j].y);
        cv.s[2*j] = t0.s; cv.s[2*j+1] = t1.s;
    }
    return cv.h;
}

// ---------------- zero init ----------------
__global__ __launch_bounds__(256) void k_zero(float* __restrict__ hdr, float* __restrict__ out)
{
    int idx = blockIdx.x * 256 + threadIdx.x;
    if (idx < NB) out[idx] = 0.f;
    if (idx < 6240) hdr[idx] = 0.f;
}

// ---------------- weight prep: Wcat^T [DOUT][5*DIN] bf16 ----------------
template<int DIN, int DOUT>
__global__ __launch_bounds__(256) void k_prep(const float* __restrict__ ws,
                                              const float* __restrict__ wr,
                                              bf16* __restrict__ wt)
{
    constexpr int K5 = 5*DIN;
    int idx = blockIdx.x*256 + threadIdx.x;
    if (idx >= DOUT*K5) return;
    int n = idx / K5, k = idx % K5;
    int s = k / DIN, kk = k % DIN;
    float v = (s == 0) ? ws[(size_t)kk*DOUT + n]
                       : wr[((size_t)(s-1)*DIN + kk)*DOUT + n];
    wt[idx] = f2bf(v);
}

// ---------------- layer 0 (din=5) ----------------
__global__ __launch_bounds__(256) void k_layer0(
    const float* __restrict__ feats, const float* __restrict__ adj,
    const float* __restrict__ ws, const float* __restrict__ wr,
    const float* __restrict__ bias, bf16* __restrict__ hpre, float* __restrict__ slots)
{
    __shared__ float Wsh[5][5][64];
    __shared__ float Bsh[64];
    __shared__ float Adj[4][4][9][9];
    __shared__ float Hsh[4][9][5];
    __shared__ float bstat[18];

    int tid = threadIdx.x;
    int bl  = tid >> 6;
    int e   = tid & 63;
    int b0  = blockIdx.x * 4;

    for (int i = tid; i < 5*64; i += 256) Wsh[0][i/64][i%64] = ws[i];
    for (int i = tid; i < 4*5*64; i += 256) {
        int s = i / 320, rem = i % 320;
        Wsh[1+s][rem/64][rem%64] = wr[i];
    }
    if (tid < 64) Bsh[tid] = bias[tid];
    if (tid < 18) bstat[tid] = 0.f;
    {
        const float* ap = adj + (size_t)(b0 + bl) * (NR*NA*NA);
        float* dst = &Adj[bl][0][0][0];
        for (int i = e; i < NR*NA*NA; i += 64) dst[i] = ap[i];
    }
    {
        const float* fp = feats + (size_t)(b0 + bl) * (NA*D0);
        float* dst = &Hsh[bl][0][0];
        for (int i = e; i < NA*D0; i += 64) dst[i] = fp[i];
    }
    __syncthreads();

    float X[5][9];
    #pragma unroll
    for (int s = 0; s < 5; s++)
        #pragma unroll
        for (int n = 0; n < 9; n++) {
            float a = 0.f;
            #pragma unroll
            for (int k = 0; k < 5; k++) a += Hsh[bl][n][k] * Wsh[s][k][e];
            X[s][n] = a;
        }
    float bv = Bsh[e];
    float out[9];
    #pragma unroll
    for (int m = 0; m < 9; m++) {
        float a = X[0][m] + bv;
        #pragma unroll
        for (int r = 0; r < 4; r++)
            #pragma unroll
            for (int n = 0; n < 9; n++)
                a += Adj[bl][r][m][n] * X[1+r][n];
        out[m] = a;
    }
    bf16* hp = hpre + (size_t)(b0 + bl) * (NA*D1) + e;
    #pragma unroll
    for (int m = 0; m < 9; m++) hp[m*D1] = f2bf(out[m]);

    #pragma unroll
    for (int m = 0; m < 9; m++) {
        float s = out[m], q = out[m]*out[m];
        #pragma unroll
        for (int off = 32; off > 0; off >>= 1) {
            s += __shfl_xor(s, off, 64);
            q += __shfl_xor(q, off, 64);
        }
        if (e == 0) { atomicAdd(&bstat[m], s); atomicAdd(&bstat[9+m], q); }
    }
    __syncthreads();
    if (tid < 9) {
        float* sl = slots + (size_t)(blockIdx.x & (NSLOT-1)) * 32;
        atomicAdd(&sl[tid],      bstat[tid]);
        atomicAdd(&sl[16+tid],   bstat[9+tid]);
    }
}

// ---------------- BN finalize ----------------
template<int DOUT>
__global__ void k_finalize(const float* __restrict__ slots,
                           const float* __restrict__ g, const float* __restrict__ be,
                           float* __restrict__ fin)
{
    int n = threadIdx.x;
    if (n < 9) {
        float s = 0.f, q = 0.f;
        for (int i = 0; i < NSLOT; i++) { s += slots[i*32+n]; q += slots[i*32+16+n]; }
        float cnt = (float)NB * (float)DOUT;
        float mean = s / cnt;
        float var  = q / cnt - mean*mean;
        float sc   = g[n] * rsqrtf(var + EPS);
        fin[n]    = sc;
        fin[16+n] = be[n] - mean * sc;
    }
}

// ---------------- buildY: one 32-col chunk, all 4 relations ----------------
template<int DIN>
__device__ __forceinline__ void buildY(const bf16* __restrict__ hS,
                                       const float adjR[4][9],
                                       int bml, int brow, int bc8, int kc,
                                       bf16* __restrict__ ydst)
{
    constexpr int HS = DIN + 8;
    const bf16* hb = hS + (size_t)(bml*9)*HS + kc*32 + bc8;
    f32x2 y[4][4];
    #pragma unroll
    for (int r = 0; r < 4; r++)
        #pragma unroll
        for (int j = 0; j < 4; j++) y[r][j] = (f32x2){0.f, 0.f};
    #pragma unroll
    for (int n = 0; n < 9; n++) {
        bf16x8 hv = *(const bf16x8*)(hb + n*HS);
        f32x2 hf[4]; cvt8(hv, hf);
        #pragma unroll
        for (int r = 0; r < 4; r++) {
            f32x2 av = (f32x2){adjR[r][n], adjR[r][n]};
            #pragma unroll
            for (int j = 0; j < 4; j++)
                y[r][j] = __builtin_elementwise_fma(av, hf[j], y[r][j]);
        }
    }
    #pragma unroll
    for (int r = 0; r < 4; r++)
        *(bf16x8*)(&ydst[(r*64 + brow)*YST + bc8]) = pack8(y[r]);
}

// ---------------- fused RGCN layer (MFMA) ----------------
// MODE 0: store hout + stats.  MODE 1: stats only.  MODE 2: fused readout epilogue.
template<int DIN, int DOUT, int MODE>
__global__ __launch_bounds__(256, 2) void k_mfma(
    const bf16*  __restrict__ hprev,   // [B,9,DIN]
    const float* __restrict__ finPrev, // prev-layer BN affine [32]
    const float* __restrict__ adjg,    // [B,4,9,9]
    const bf16*  __restrict__ wt,      // [DOUT][5*DIN] bf16 (Wcat^T)
    const float* __restrict__ bias,    // [DOUT]
    bf16*  __restrict__ hout,          // (MODE 0)
    float* __restrict__ slots,         // (MODE 0/1)
    const float* __restrict__ finC,    // (MODE 2)
    const float* __restrict__ maskg,   // (MODE 2)
    const float* __restrict__ fcw,     // (MODE 2)
    float* __restrict__ outp)          // (MODE 2)
{
    constexpr int K5 = 5*DIN;
    constexpr int HS = DIN + 8;
    constexpr int NT = DOUT/64;
    constexpr int KS = DIN/32;
    constexpr int HW8 = DIN/8;

    __shared__ __align__(16) bf16 hS[81*HS];
    __shared__ __align__(16) bf16 yS[2][4*64*YST];
    __shared__ float rstat[128];
    __shared__ float sfinP[32];
    __shared__ float sfinC[32];

    int tid = threadIdx.x;
    int row0 = blockIdx.x * 64;
    int mol_lo = row0 / 9;
    int mol_hi = (row0 + 63) / 9;
    int nmol = mol_hi - mol_lo + 1;
    int off = row0 - mol_lo*9;

    if (tid < 32) sfinP[tid] = finPrev[tid];
    if constexpr (MODE == 2) { if (tid >= 32 && tid < 64) sfinC[tid-32] = finC[tid-32]; }
    if (tid >= 64 && tid < 192) rstat[tid-64] = 0.f;

    // buildY assignment: thread -> (row brow, 8-col group bc8); its adj rows in registers
    int brow = tid >> 2;
    int bc8  = (tid & 3) * 8;
    int bloc = off + brow;
    int bml  = bloc / 9;
    int ba   = bloc - bml*9;
    float adjR[4][9];
    {
        const float* ap = adjg + (size_t)(mol_lo + bml)*324 + ba*9;
        #pragma unroll
        for (int r = 0; r < 4; r++)
            #pragma unroll
            for (int n = 0; n < 9; n++) adjR[r][n] = ap[r*81 + n];
    }
    __syncthreads();

    // stage act(h_prev) -> hS: affine(prev BN) + leaky, bf16, padded rows
    for (int i = tid; i < nmol*9*HW8; i += 256) {
        int rl = i / HW8;
        int a  = rl % 9;
        int c8 = (i % HW8)*8;
        bf16x8 hv = *(const bf16x8*)(hprev + (size_t)(mol_lo*9 + rl)*DIN + c8);
        f32x2 hf[4]; cvt8(hv, hf);
        float sc = sfinP[a], sh = sfinP[16+a];
        f32x2 o[4];
        #pragma unroll
        for (int j = 0; j < 4; j++) {
            float v0 = sc*hf[j].x + sh; v0 = fmaxf(v0, SLOPE*v0);
            float v1 = sc*hf[j].y + sh; v1 = fmaxf(v1, SLOPE*v1);
            o[j] = (f32x2){v0, v1};
        }
        *(bf16x8*)(&hS[rl*HS + c8]) = pack8(o);
    }
    __syncthreads();

    int wv = tid >> 6, lane = tid & 63;
    int q = lane >> 4, l15 = lane & 15;

    f32x4 acc[4][NT];
    #pragma unroll
    for (int mt = 0; mt < 4; mt++)
        #pragma unroll
        for (int t = 0; t < NT; t++) acc[mt][t] = (f32x4){0.f, 0.f, 0.f, 0.f};

    const bf16* wp[NT];
    #pragma unroll
    for (int t = 0; t < NT; t++)
        wp[t] = wt + (size_t)((wv*NT + t)*16 + l15)*K5 + q*8;

    // --- self section: A-frags from hS ---
    #pragma unroll
    for (int ks = 0; ks < KS; ks++) {
        bf16x8 Af[4], Bf[NT];
        #pragma unroll
        for (int mt = 0; mt < 4; mt++)
            Af[mt] = *(const bf16x8*)(hS + (size_t)(off + mt*16 + l15)*HS + ks*32 + q*8);
        #pragma unroll
        for (int t = 0; t < NT; t++)
            Bf[t] = *(const bf16x8*)(wp[t] + ks*32);
        #pragma unroll
        for (int mt = 0; mt < 4; mt++)
            #pragma unroll
            for (int t = 0; t < NT; t++)
                acc[mt][t] = __builtin_amdgcn_mfma_f32_16x16x32_bf16(Af[mt], Bf[t], acc[mt][t], 0, 0, 0);
    }

    // --- relation sections: double-buffered, ONE barrier per chunk ---
    buildY<DIN>(hS, adjR, bml, brow, bc8, 0, yS[0]);
    __syncthreads();
    for (int kc = 0; kc < KS; kc++) {
        const bf16* yb = yS[kc & 1];
        #pragma unroll
        for (int r = 0; r < 4; r++) {
            int kcol = (1+r)*DIN + kc*32;
            bf16x8 Af[4], Bf[NT];
            #pragma unroll
            for (int mt = 0; mt < 4; mt++)
                Af[mt] = *(const bf16x8*)(&yb[(r*64 + mt*16 + l15)*YST + q*8]);
            #pragma unroll
            for (int t = 0; t < NT; t++)
                Bf[t] = *(const bf16x8*)(wp[t] + kcol);
            #pragma unroll
            for (int mt = 0; mt < 4; mt++)
                #pragma unroll
                for (int t = 0; t < NT; t++)
                    acc[mt][t] = __builtin_amdgcn_mfma_f32_16x16x32_bf16(Af[mt], Bf[t], acc[mt][t], 0, 0, 0);
        }
        if (kc + 1 < KS)
            buildY<DIN>(hS, adjR, bml, brow, bc8, kc + 1, yS[(kc + 1) & 1]);
        __syncthreads();
    }

    // --- epilogue ---
    float bcol[NT];
    #pragma unroll
    for (int t = 0; t < NT; t++) bcol[t] = bias[(wv*NT + t)*16 + l15];

    if constexpr (MODE == 2) {
        float fwv[NT];
        #pragma unroll
        for (int t = 0; t < NT; t++) fwv[t] = fcw[(wv*NT + t)*16 + l15];
        #pragma unroll
        for (int mt = 0; mt < 4; mt++) {
            #pragma unroll
            for (int reg = 0; reg < 4; reg++) {
                int rloc = mt*16 + q*4 + reg;
                int atom = (row0 + rloc) % 9;
                float sc = sfinC[atom], sh = sfinC[16+atom];
                float part = 0.f;
                #pragma unroll
                for (int t = 0; t < NT; t++) {
                    float v = acc[mt][t][reg] + bcol[t];
                    float y = sc*v + sh;
                    y = fmaxf(y, SLOPE*y);
                    part += y * fwv[t];
                }
                part += __shfl_xor(part, 1); part += __shfl_xor(part, 2);
                part += __shfl_xor(part, 4); part += __shfl_xor(part, 8);
                if (l15 == 0) atomicAdd(&rstat[rloc], part);
            }
        }
        __syncthreads();
        if (tid < 64) {
            int rg = row0 + tid;
            int b = rg / 9;
            atomicAdd(&outp[b], rstat[tid] * maskg[rg]);
        }
        return;
    }

    #pragma unroll
    for (int mt = 0; mt < 4; mt++) {
        #pragma unroll
        for (int reg = 0; reg < 4; reg++) {
            int rloc = mt*16 + q*4 + reg;
            float s = 0.f, qq = 0.f;
            #pragma unroll
            for (int t = 0; t < NT; t++) {
                float v = acc[mt][t][reg] + bcol[t];
                if constexpr (MODE == 0) {
                    size_t o = (size_t)(row0 + rloc)*DOUT + (wv*NT + t)*16 + l15;
                    hout[o] = f2bf(v);
                }
                s += v; qq += v*v;
            }
            s += __shfl_xor(s, 1); s += __shfl_xor(s, 2);
            s += __shfl_xor(s, 4); s += __shfl_xor(s, 8);
            qq += __shfl_xor(qq, 1); qq += __shfl_xor(qq, 2);
            qq += __shfl_xor(qq, 4); qq += __shfl_xor(qq, 8);
            if (l15 == 0) { atomicAdd(&rstat[rloc*2], s); atomicAdd(&rstat[rloc*2+1], qq); }
        }
    }
    __syncthreads();
    if (tid < 64) {
        int rg = row0 + tid;
        int atom = rg % 9;
        float* sl = slots + (size_t)(blockIdx.x & (NSLOT-1))*32;
        atomicAdd(&sl[atom],    rstat[tid*2]);
        atomicAdd(&sl[16+atom], rstat[tid*2+1]);
    }
}

// ---------------- Path-A readout ----------------
__global__ __launch_bounds__(256) void k_readout(
    const bf16* __restrict__ h2, const float* __restrict__ fin,
    const float* __restrict__ mask, const float* __restrict__ fcw,
    const float* __restrict__ fcb, float* __restrict__ out)
{
    int tid = threadIdx.x;
    int w = tid >> 6, lane = tid & 63;
    int b = blockIdx.x * 4 + w;
    float sc[9], sh[9];
    #pragma unroll
    for (int n = 0; n < 9; n++) { sc[n] = fin[n]; sh[n] = fin[16+n]; }
    const bf16* hp = h2 + (size_t)b * (NA*D3) + lane*4;
    float acc0 = 0.f, acc1 = 0.f, acc2 = 0.f, acc3 = 0.f;
    #pragma unroll
    for (int n = 0; n < 9; n++) {
        bf16 v4[4] __attribute__((aligned(8)));
        *(uint2*)v4 = *(const uint2*)(hp + n*D3);
        float mk = mask[(size_t)b*NA + n];
        float v;
        v = sc[n]*bf2f(v4[0]) + sh[n]; v = fmaxf(v, SLOPE*v); acc0 += v*mk;
        v = sc[n]*bf2f(v4[1]) + sh[n]; v = fmaxf(v, SLOPE*v); acc1 += v*mk;
        v = sc[n]*bf2f(v4[2]) + sh[n]; v = fmaxf(v, SLOPE*v); acc2 += v*mk;
        v = sc[n]*bf2f(v4[3]) + sh[n]; v = fmaxf(v, SLOPE*v); acc3 += v*mk;
    }
    float4 wv = *(const float4*)(fcw + lane*4);
    float s = acc0*wv.x + acc1*wv.y + acc2*wv.z + acc3*wv.w;
    #pragma unroll
    for (int off = 1; off < 64; off <<= 1) s += __shfl_xor(s, off, 64);
    if (lane == 0) out[b] = s + fcb[0];
}

__global__ __launch_bounds__(256) void k_addfcb(float* __restrict__ out, const float* __restrict__ fcb)
{
    int idx = blockIdx.x * 256 + threadIdx.x;
    if (idx < NB) out[idx] += fcb[0];
}

// ---------------- workspace layout ----------------
// [0, 24960)      : slots 3*64*32 f + fins 3*32 f
// [32768, 114688) : wt1 bf16 [128][320]
// [114688, 442368): wt2 bf16 [256][640]
// Path A: h1 @524288 (75,497,472); h2 @76,021,760 (150,994,944); h0 aliased at h2 base.
//         End = 227,016,704 (ws confirmed >= 250,118,144 by R2 Path-A pass).
// Path B: h0 @524288; h1 @38,273,024. End = 113,770,496.

extern "C" void kernel_launch(void* const* d_in, const int* in_sizes, int n_in,
                              void* d_out, int out_size, void* d_ws, size_t ws_size,
                              hipStream_t stream)
{
    const float* feats = (const float*)d_in[0];
    const float* adj   = (const float*)d_in[1];
    const float* mask  = (const float*)d_in[2];
    const float* ws0 = (const float*)d_in[3];
    const float* wr0 = (const float*)d_in[4];
    const float* b0  = (const float*)d_in[5];
    const float* g0  = (const float*)d_in[6];
    const float* be0 = (const float*)d_in[7];
    const float* ws1 = (const float*)d_in[8];
    const float* wr1 = (const float*)d_in[9];
    const float* b1  = (const float*)d_in[10];
    const float* g1  = (const float*)d_in[11];
    const float* be1 = (const float*)d_in[12];
    const float* ws2 = (const float*)d_in[13];
    const float* wr2 = (const float*)d_in[14];
    const float* b2  = (const float*)d_in[15];
    const float* g2  = (const float*)d_in[16];
    const float* be2 = (const float*)d_in[17];
    const float* fcw = (const float*)d_in[18];
    const float* fcb = (const float*)d_in[19];
    float* outp = (float*)d_out;

    char* wsb = (char*)d_ws;
    float* slots0 = (float*)(wsb + 0);
    float* slots1 = slots0 + NSLOT*32;
    float* slots2 = slots1 + NSLOT*32;
    float* fin0 = (float*)(wsb + 24576);
    float* fin1 = fin0 + 32;
    float* fin2 = fin1 + 32;
    bf16* wt1 = (bf16*)(wsb + 32768);
    bf16* wt2 = (bf16*)(wsb + 114688);

    k_zero<<<(NB+255)/256, 256, 0, stream>>>((float*)wsb, outp);
    k_prep<D1, D2><<<(D2*5*D1 + 255)/256, 256, 0, stream>>>(ws1, wr1, wt1);
    k_prep<D2, D3><<<(D3*5*D2 + 255)/256, 256, 0, stream>>>(ws2, wr2, wt2);

    bool bigws = (ws_size >= 227016704ULL);
    const int GRID = (NB*NA)/64;   // 4608

    if (bigws) {
        bf16* h1 = (bf16*)(wsb + 524288ULL);
        bf16* h2 = (bf16*)(wsb + 76021760ULL);
        bf16* h0 = h2;   // alias: h0 fully consumed before first h2 write

        k_layer0<<<NB/4, 256, 0, stream>>>(feats, adj, ws0, wr0, b0, h0, slots0);
        k_finalize<D1><<<1, 64, 0, stream>>>(slots0, g0, be0, fin0);

        k_mfma<D1, D2, 0><<<GRID, 256, 0, stream>>>(
            h0, fin0, adj, wt1, b1, h1, slots1, nullptr, nullptr, nullptr, nullptr);
        k_finalize<D2><<<1, 64, 0, stream>>>(slots1, g1, be1, fin1);

        k_mfma<D2, D3, 0><<<GRID, 256, 0, stream>>>(
            h1, fin1, adj, wt2, b2, h2, slots2, nullptr, nullptr, nullptr, nullptr);
        k_finalize<D3><<<1, 64, 0, stream>>>(slots2, g2, be2, fin2);

        k_readout<<<NB/4, 256, 0, stream>>>(h2, fin2, mask, fcw, fcb, outp);
    } else {
        bf16* h0 = (bf16*)(wsb + 524288ULL);
        bf16* h1 = (bf16*)(wsb + 38273024ULL);

        k_layer0<<<NB/4, 256, 0, stream>>>(feats, adj, ws0, wr0, b0, h0, slots0);
        k_finalize<D1><<<1, 64, 0, stream>>>(slots0, g0, be0, fin0);

        k_mfma<D1, D2, 0><<<GRID, 256, 0, stream>>>(
            h0, fin0, adj, wt1, b1, h1, slots1, nullptr, nullptr, nullptr, nullptr);
        k_finalize<D2><<<1, 64, 0, stream>>>(slots1, g1, be1, fin1);

        k_mfma<D2, D3, 1><<<GRID, 256, 0, stream>>>(
            h1, fin1, adj, wt2, b2, nullptr, slots2, nullptr, nullptr, nullptr, nullptr);
        k_finalize<D3><<<1, 64, 0, stream>>>(slots2, g2, be2, fin2);

        k_mfma<D2, D3, 2><<<GRID, 256, 0, stream>>>(
            h1, fin1, adj, wt2, b2, nullptr, nullptr, fin2, mask, fcw, outp);
        k_addfcb<<<(NB+255)/256, 256, 0, stream>>>(outp, fcb);
    }
}